// Round 1
// baseline (2972.187 us; speedup 1.0000x reference)
//
#include <hip/hip_runtime.h>
#include <math.h>

#define DFEAT 256
#define KITER 10
#define ALPHA 0.1f
#define BETA 0.9f

// ---------------- setup kernels ----------------

__global__ void count_deg_kernel(const int* __restrict__ row,
                                 const float* __restrict__ w,
                                 float* __restrict__ deg,
                                 int* __restrict__ counts, int E) {
    int e = blockIdx.x * 256 + threadIdx.x;
    if (e < E) {
        int r = row[e];
        atomicAdd(&deg[r], w[e]);
        atomicAdd(&counts[r], 1);
    }
}

// deg -> dinv in place. Self-loop adds weight 1 to every degree, so deg+1 > 0 always.
__global__ void dinv_kernel(float* __restrict__ deg, int n) {
    int i = blockIdx.x * 256 + threadIdx.x;
    if (i < n) deg[i] = rsqrtf(deg[i] + 1.0f);
}

// Single-block exclusive scan of counts[0..n) -> row_ptr[0..n], also copies to fill[].
__global__ void scan_kernel(const int* __restrict__ counts,
                            int* __restrict__ row_ptr,
                            int* __restrict__ fill, int n) {
    __shared__ int tmp[1024];
    int tid = threadIdx.x;
    int carry = 0;
    for (int base = 0; base < n; base += 1024) {
        int i = base + tid;
        int v = (i < n) ? counts[i] : 0;
        tmp[tid] = v;
        __syncthreads();
        // Hillis-Steele inclusive scan
        for (int off = 1; off < 1024; off <<= 1) {
            int t = (tid >= off) ? tmp[tid - off] : 0;
            __syncthreads();
            tmp[tid] += t;
            __syncthreads();
        }
        int incl = tmp[tid];
        int excl = incl - v + carry;
        if (i < n) { row_ptr[i] = excl; fill[i] = excl; }
        int total = tmp[1023];
        __syncthreads();   // protect tmp before next tile overwrite
        carry += total;
    }
    if (tid == 0) row_ptr[n] = carry;
}

// Scatter edges into CSR slots; fuse normalized weight dinv[r]*w*dinv[c]; pack (col, w) in 8B.
__global__ void scatter_kernel(const int* __restrict__ row, const int* __restrict__ col,
                               const float* __restrict__ w, const float* __restrict__ dinv,
                               int* __restrict__ fill, int2* __restrict__ cw, int E) {
    int e = blockIdx.x * 256 + threadIdx.x;
    if (e < E) {
        int r = row[e], c = col[e];
        float wn = dinv[r] * w[e] * dinv[c];
        int pos = atomicAdd(&fill[r], 1);
        cw[pos] = make_int2(c, __float_as_int(wn));
    }
}

// ---------------- main SpMM iteration ----------------
// out[r] = scale * (BETA * (A_norm @ in)[r] + ALPHA * x[r])
// One wave (64 lanes) per row; lane owns 4 consecutive dims via float4.
__global__ __launch_bounds__(256) void spmm_kernel(
        const float* __restrict__ in, const float* __restrict__ x,
        float* __restrict__ out,
        const int* __restrict__ row_ptr, const int2* __restrict__ cw,
        const float* __restrict__ dinv,
        int n, float scale) {
    int wave = threadIdx.x >> 6;
    int lane = threadIdx.x & 63;
    int r = blockIdx.x * 4 + wave;
    if (r >= n) return;

    int start = row_ptr[r];
    int end   = row_ptr[r + 1];
    float dr  = dinv[r];
    float ws  = dr * dr;  // self-loop normalized weight

    const float4* inr = (const float4*)(in + (size_t)r * DFEAT);
    float4 s = inr[lane];
    float4 acc = make_float4(ws * s.x, ws * s.y, ws * s.z, ws * s.w);

    for (int e = start; e < end; ++e) {
        int2 p = cw[e];
        float wv = __int_as_float(p.y);
        const float4* inc = (const float4*)(in + (size_t)p.x * DFEAT);
        float4 v = inc[lane];
        acc.x += wv * v.x;
        acc.y += wv * v.y;
        acc.z += wv * v.z;
        acc.w += wv * v.w;
    }

    const float4* xr = (const float4*)(x + (size_t)r * DFEAT);
    float4 xv = xr[lane];
    float4 o;
    o.x = scale * (BETA * acc.x + ALPHA * xv.x);
    o.y = scale * (BETA * acc.y + ALPHA * xv.y);
    o.z = scale * (BETA * acc.z + ALPHA * xv.z);
    o.w = scale * (BETA * acc.w + ALPHA * xv.w);
    ((float4*)(out + (size_t)r * DFEAT))[lane] = o;
}

// ---------------- launch ----------------

extern "C" void kernel_launch(void* const* d_in, const int* in_sizes, int n_in,
                              void* d_out, int out_size, void* d_ws, size_t ws_size,
                              hipStream_t stream) {
    const float* x  = (const float*)d_in[0];
    const float* ew = (const float*)d_in[1];
    const int*   ei = (const int*)d_in[2];
    int n = in_sizes[0] / DFEAT;
    int E = in_sizes[1];
    const int* row = ei;        // edge_index[0]
    const int* col = ei + E;    // edge_index[1]
    float* out = (float*)d_out;

    // carve workspace
    char* ws = (char*)d_ws;
    auto alloc = [&](size_t bytes) {
        char* p = ws;
        ws += (bytes + 255) & ~(size_t)255;
        return p;
    };
    float* deg     = (float*)alloc((size_t)n * 4);       // becomes dinv in place
    int*   counts  = (int*)  alloc((size_t)n * 4);
    int*   row_ptr = (int*)  alloc((size_t)(n + 1) * 4);
    int*   fill    = (int*)  alloc((size_t)n * 4);
    int2*  cw      = (int2*) alloc((size_t)E * 8);
    float* P0      = (float*)alloc((size_t)n * DFEAT * 4);

    hipMemsetAsync(deg, 0, (size_t)n * 4, stream);
    hipMemsetAsync(counts, 0, (size_t)n * 4, stream);

    count_deg_kernel<<<(E + 255) / 256, 256, 0, stream>>>(row, ew, deg, counts, E);
    dinv_kernel<<<(n + 255) / 256, 256, 0, stream>>>(deg, n);
    scan_kernel<<<1, 1024, 0, stream>>>(counts, row_ptr, fill, n);
    scatter_kernel<<<(E + 255) / 256, 256, 0, stream>>>(row, col, ew, deg, fill, cw, E);

    // GAMMA = BETA^K + ALPHA * sum_{i<K} BETA^i  (== 1.0 exactly for these constants)
    double gamma = pow((double)BETA, KITER);
    for (int i = 0; i < KITER; ++i) gamma += (double)ALPHA * pow((double)BETA, i);
    float inv_gamma = (float)(1.0 / gamma);

    int grid = (n + 3) / 4;
    const float* cur = x;
    float* bufs[2] = { P0, out };   // k even -> P0, k odd -> out; k=9 lands in out
    for (int k = 0; k < KITER; ++k) {
        float* o = bufs[k & 1];
        float scale = (k == KITER - 1) ? inv_gamma : 1.0f;
        spmm_kernel<<<grid, 256, 0, stream>>>(cur, x, o, row_ptr, cw, deg, n, scale);
        cur = o;
    }
}

// Round 2
// 1701.200 us; speedup vs baseline: 1.7471x; 1.7471x over previous
//
#include <hip/hip_runtime.h>
#include <hip/hip_fp16.h>
#include <math.h>

#define DFEAT 256
#define KITER 10
#define ALPHA 0.1f
#define BETA 0.9f

// ---------------- setup kernels ----------------

__global__ void count_deg_kernel(const int* __restrict__ row,
                                 const float* __restrict__ w,
                                 float* __restrict__ deg,
                                 int* __restrict__ counts, int E) {
    int e = blockIdx.x * 256 + threadIdx.x;
    if (e < E) {
        int r = row[e];
        atomicAdd(&deg[r], w[e]);
        atomicAdd(&counts[r], 1);
    }
}

// deg -> dinv in place. Self-loop adds weight 1, so deg+1 > 0 always.
__global__ void dinv_kernel(float* __restrict__ deg, int n) {
    int i = blockIdx.x * 256 + threadIdx.x;
    if (i < n) deg[i] = rsqrtf(deg[i] + 1.0f);
}

// Single-block exclusive scan of counts[0..n) -> row_ptr[0..n], copy to fill[].
__global__ void scan_kernel(const int* __restrict__ counts,
                            int* __restrict__ row_ptr,
                            int* __restrict__ fill, int n) {
    __shared__ int tmp[1024];
    int tid = threadIdx.x;
    int carry = 0;
    for (int base = 0; base < n; base += 1024) {
        int i = base + tid;
        int v = (i < n) ? counts[i] : 0;
        tmp[tid] = v;
        __syncthreads();
        for (int off = 1; off < 1024; off <<= 1) {
            int t = (tid >= off) ? tmp[tid - off] : 0;
            __syncthreads();
            tmp[tid] += t;
            __syncthreads();
        }
        int incl = tmp[tid];
        int excl = incl - v + carry;
        if (i < n) { row_ptr[i] = excl; fill[i] = excl; }
        int total = tmp[1023];
        __syncthreads();
        carry += total;
    }
    if (tid == 0) row_ptr[n] = carry;
}

// Scatter edges into CSR; fused normalized weight dinv[r]*w*dinv[c]; pack (col,w) 8B.
__global__ void scatter_kernel(const int* __restrict__ row, const int* __restrict__ col,
                               const float* __restrict__ w, const float* __restrict__ dinv,
                               int* __restrict__ fill, int2* __restrict__ cw, int E) {
    int e = blockIdx.x * 256 + threadIdx.x;
    if (e < E) {
        int r = row[e], c = col[e];
        float wn = dinv[r] * w[e] * dinv[c];
        int pos = atomicAdd(&fill[r], 1);
        cw[pos] = make_int2(c, __float_as_int(wn));
    }
}

// fp32 -> fp16, 4 elements per thread (8B stores)
__global__ void f2h_kernel(const float* __restrict__ src, __half* __restrict__ dst,
                           size_t n4) {
    size_t i = (size_t)blockIdx.x * 256 + threadIdx.x;
    if (i < n4) {
        float4 v = ((const float4*)src)[i];
        __half2 h0 = __floats2half2_rn(v.x, v.y);
        __half2 h1 = __floats2half2_rn(v.z, v.w);
        float2 o;
        o.x = *reinterpret_cast<float*>(&h0);
        o.y = *reinterpret_cast<float*>(&h1);
        ((float2*)dst)[i] = o;
    }
}

// ---------------- main SpMM iteration (fp16 state, fp32 accumulate) ---------
// out[r] = scale * (BETA * (A_norm @ in)[r] + ALPHA * x[r])
// One wave per row; lane owns 4 feats (8B fp16 load per lane = 512B/row).
#define ACC(g, wbits) { float wv = __int_as_float(wbits); \
    __half2 h0_ = *reinterpret_cast<__half2*>(&g.x); \
    __half2 h1_ = *reinterpret_cast<__half2*>(&g.y); \
    float2 u0_ = __half22float2(h0_); float2 u1_ = __half22float2(h1_); \
    a0 += wv * u0_.x; a1 += wv * u0_.y; a2 += wv * u1_.x; a3 += wv * u1_.y; }

template<int FINAL>
__global__ __launch_bounds__(256) void spmm_h_kernel(
        const __half* __restrict__ in, const __half* __restrict__ xh,
        float* __restrict__ outf, __half* __restrict__ outh,
        const int* __restrict__ row_ptr, const int2* __restrict__ cw,
        const float* __restrict__ dinv,
        int n, float scale) {
    int wave = threadIdx.x >> 6;
    int lane = threadIdx.x & 63;
    int r = blockIdx.x * 4 + wave;
    if (r >= n) return;

    int start = row_ptr[r];
    int end   = row_ptr[r + 1];
    float dr  = dinv[r];
    float ws  = dr * dr;

    // issue x load early (independent of edge loop)
    float2 xraw = ((const float2*)(xh + (size_t)r * DFEAT))[lane];

    float2 sraw = ((const float2*)(in + (size_t)r * DFEAT))[lane];
    __half2 s0 = *reinterpret_cast<__half2*>(&sraw.x);
    __half2 s1 = *reinterpret_cast<__half2*>(&sraw.y);
    float2 sf0 = __half22float2(s0), sf1 = __half22float2(s1);
    float a0 = ws * sf0.x, a1 = ws * sf0.y, a2 = ws * sf1.x, a3 = ws * sf1.y;

    int e = start;
    for (; e + 4 <= end; e += 4) {
        int2 p0 = cw[e];
        int2 p1 = cw[e + 1];
        int2 p2 = cw[e + 2];
        int2 p3 = cw[e + 3];
        float2 g0 = ((const float2*)(in + (size_t)p0.x * DFEAT))[lane];
        float2 g1 = ((const float2*)(in + (size_t)p1.x * DFEAT))[lane];
        float2 g2 = ((const float2*)(in + (size_t)p2.x * DFEAT))[lane];
        float2 g3 = ((const float2*)(in + (size_t)p3.x * DFEAT))[lane];
        ACC(g0, p0.y);
        ACC(g1, p1.y);
        ACC(g2, p2.y);
        ACC(g3, p3.y);
    }
    for (; e < end; ++e) {
        int2 p = cw[e];
        float2 g = ((const float2*)(in + (size_t)p.x * DFEAT))[lane];
        ACC(g, p.y);
    }

    __half2 x0 = *reinterpret_cast<__half2*>(&xraw.x);
    __half2 x1 = *reinterpret_cast<__half2*>(&xraw.y);
    float2 xf0 = __half22float2(x0), xf1 = __half22float2(x1);
    float o0 = scale * (BETA * a0 + ALPHA * xf0.x);
    float o1 = scale * (BETA * a1 + ALPHA * xf0.y);
    float o2 = scale * (BETA * a2 + ALPHA * xf1.x);
    float o3 = scale * (BETA * a3 + ALPHA * xf1.y);

    if (FINAL) {
        ((float4*)(outf + (size_t)r * DFEAT))[lane] = make_float4(o0, o1, o2, o3);
    } else {
        __half2 h0 = __floats2half2_rn(o0, o1);
        __half2 h1 = __floats2half2_rn(o2, o3);
        float2 o;
        o.x = *reinterpret_cast<float*>(&h0);
        o.y = *reinterpret_cast<float*>(&h1);
        ((float2*)(outh + (size_t)r * DFEAT))[lane] = o;
    }
}

// ---------------- launch ----------------

extern "C" void kernel_launch(void* const* d_in, const int* in_sizes, int n_in,
                              void* d_out, int out_size, void* d_ws, size_t ws_size,
                              hipStream_t stream) {
    const float* x  = (const float*)d_in[0];
    const float* ew = (const float*)d_in[1];
    const int*   ei = (const int*)d_in[2];
    int n = in_sizes[0] / DFEAT;
    int E = in_sizes[1];
    const int* row = ei;
    const int* col = ei + E;
    float* out = (float*)d_out;

    char* ws = (char*)d_ws;
    auto alloc = [&](size_t bytes) {
        char* p = ws;
        ws += (bytes + 255) & ~(size_t)255;
        return p;
    };
    float*  deg     = (float*)alloc((size_t)n * 4);   // becomes dinv in place
    int*    counts  = (int*)  alloc((size_t)n * 4);
    int*    row_ptr = (int*)  alloc((size_t)(n + 1) * 4);
    int*    fill    = (int*)  alloc((size_t)n * 4);
    int2*   cw      = (int2*) alloc((size_t)E * 8);
    __half* xh      = (__half*)alloc((size_t)n * DFEAT * 2);
    __half* H0      = (__half*)alloc((size_t)n * DFEAT * 2);
    __half* H1      = (__half*)d_out;   // alias: dead before final fp32 write

    hipMemsetAsync(deg, 0, (size_t)n * 4, stream);
    hipMemsetAsync(counts, 0, (size_t)n * 4, stream);

    count_deg_kernel<<<(E + 255) / 256, 256, 0, stream>>>(row, ew, deg, counts, E);
    dinv_kernel<<<(n + 255) / 256, 256, 0, stream>>>(deg, n);
    scan_kernel<<<1, 1024, 0, stream>>>(counts, row_ptr, fill, n);
    scatter_kernel<<<(E + 255) / 256, 256, 0, stream>>>(row, col, ew, deg, fill, cw, E);

    size_t n4 = (size_t)n * DFEAT / 4;
    f2h_kernel<<<(int)((n4 + 255) / 256), 256, 0, stream>>>(x, xh, n4);

    // GAMMA == 1.0 exactly for these constants, but compute anyway.
    double gamma = pow((double)BETA, KITER);
    for (int i = 0; i < KITER; ++i) gamma += (double)ALPHA * pow((double)BETA, i);
    float inv_gamma = (float)(1.0 / gamma);

    int grid = (n + 3) / 4;
    const __half* cur = xh;
    __half* bufs[2] = { H0, H1 };   // k even -> H0, k odd -> H1(d_out alias)
    for (int k = 0; k < KITER; ++k) {
        if (k < KITER - 1) {
            __half* o = bufs[k & 1];
            spmm_h_kernel<0><<<grid, 256, 0, stream>>>(cur, xh, nullptr, o,
                                                       row_ptr, cw, deg, n, 1.0f);
            cur = o;
        } else {
            // k=9 reads H0 (k=8 wrote H0), writes fp32 to d_out (H1 dead)
            spmm_h_kernel<1><<<grid, 256, 0, stream>>>(cur, xh, out, nullptr,
                                                       row_ptr, cw, deg, n, inv_gamma);
        }
    }
}

// Round 3
// 1555.109 us; speedup vs baseline: 1.9112x; 1.0939x over previous
//
#include <hip/hip_runtime.h>
#include <hip/hip_fp16.h>
#include <math.h>

#define DFEAT 256
#define KITER 10
#define ALPHA 0.1f
#define BETA 0.9f
#define SCAN_CHUNK 2048   // per 256-thread block, 8 elems/thread

// ---------------- setup kernels ----------------

__global__ void count_deg_kernel(const int* __restrict__ row,
                                 const float* __restrict__ w,
                                 float* __restrict__ deg,
                                 int* __restrict__ counts, int E) {
    int e = blockIdx.x * 256 + threadIdx.x;
    if (e < E) {
        int r = row[e];
        atomicAdd(&deg[r], w[e]);
        atomicAdd(&counts[r], 1);
    }
}

// deg -> dinv in place. Self-loop adds weight 1, so deg+1 > 0 always.
__global__ void dinv_kernel(float* __restrict__ deg, int n) {
    int i = blockIdx.x * 256 + threadIdx.x;
    if (i < n) deg[i] = rsqrtf(deg[i] + 1.0f);
}

// --- hierarchical scan: local block scans -> scan partials -> add offsets ---

// Each block locally exclusive-scans SCAN_CHUNK elements of counts into row_ptr
// (chunk-local values) and writes its chunk total to partial[b].
__global__ __launch_bounds__(256) void scan1_kernel(const int* __restrict__ counts,
                                                    int* __restrict__ row_ptr,
                                                    int* __restrict__ partial, int n) {
    __shared__ int wsum[4];
    int b = blockIdx.x;
    int base = b * SCAN_CHUNK;
    int tid = threadIdx.x;
    int lane = tid & 63, wv = tid >> 6;

    int v[8];
    int s = 0;
    #pragma unroll
    for (int j = 0; j < 8; ++j) {
        int i = base + tid * 8 + j;
        v[j] = (i < n) ? counts[i] : 0;
        s += v[j];
    }
    // wave-inclusive scan of per-thread sums
    int incl = s;
    #pragma unroll
    for (int off = 1; off < 64; off <<= 1) {
        int t = __shfl_up(incl, off, 64);
        if (lane >= off) incl += t;
    }
    if (lane == 63) wsum[wv] = incl;
    __syncthreads();
    int woff = 0;
    for (int w = 0; w < wv; ++w) woff += wsum[w];
    int run = woff + incl - s;   // exclusive prefix of this thread's 8-elem span
    #pragma unroll
    for (int j = 0; j < 8; ++j) {
        int i = base + tid * 8 + j;
        if (i < n) row_ptr[i] = run;
        run += v[j];
    }
    if (tid == 255) partial[b] = run;   // block total
}

// Exclusive scan of partial[0..nb) in one block (nb <= 1024).
__global__ void scan2_kernel(int* __restrict__ partial, int nb) {
    __shared__ int tmp[1024];
    int tid = threadIdx.x;
    int v = (tid < nb) ? partial[tid] : 0;
    tmp[tid] = v;
    __syncthreads();
    for (int off = 1; off < 1024; off <<= 1) {
        int t = (tid >= off) ? tmp[tid - off] : 0;
        __syncthreads();
        tmp[tid] += t;
        __syncthreads();
    }
    if (tid < nb) partial[tid] = tmp[tid] - v;
}

// Add chunk offsets; produce final row_ptr and fill copies; row_ptr[n] = E.
__global__ void scan3_kernel(int* __restrict__ row_ptr, int* __restrict__ fill,
                             const int* __restrict__ partial, int n, int E) {
    int i = blockIdx.x * 256 + threadIdx.x;
    if (i < n) {
        int v = row_ptr[i] + partial[i / SCAN_CHUNK];
        row_ptr[i] = v;
        fill[i] = v;
    } else if (i == n) {
        row_ptr[n] = E;
    }
}

// Scatter edges into CSR; fused normalized weight dinv[r]*w*dinv[c]; pack (col,w) 8B.
__global__ void scatter_kernel(const int* __restrict__ row, const int* __restrict__ col,
                               const float* __restrict__ w, const float* __restrict__ dinv,
                               int* __restrict__ fill, int2* __restrict__ cw, int E) {
    int e = blockIdx.x * 256 + threadIdx.x;
    if (e < E) {
        int r = row[e], c = col[e];
        float wn = dinv[r] * w[e] * dinv[c];
        int pos = atomicAdd(&fill[r], 1);
        cw[pos] = make_int2(c, __float_as_int(wn));
    }
}

// fp32 -> fp16, 4 elements per thread (8B stores)
__global__ void f2h_kernel(const float* __restrict__ src, __half* __restrict__ dst,
                           size_t n4) {
    size_t i = (size_t)blockIdx.x * 256 + threadIdx.x;
    if (i < n4) {
        float4 v = ((const float4*)src)[i];
        __half2 h0 = __floats2half2_rn(v.x, v.y);
        __half2 h1 = __floats2half2_rn(v.z, v.w);
        float2 o;
        o.x = *reinterpret_cast<float*>(&h0);
        o.y = *reinterpret_cast<float*>(&h1);
        ((float2*)dst)[i] = o;
    }
}

// ---------------- main SpMM iteration (fp16 state, fp32 accumulate) ---------
// out[r] = scale * (BETA * (A_norm @ in)[r] + ALPHA * x[r])
// One wave per row; lane owns 4 feats (8B fp16 load per lane = 512B/row).
#define ACC(g, wbits) { float wv = __int_as_float(wbits); \
    __half2 h0_ = *reinterpret_cast<__half2*>(&g.x); \
    __half2 h1_ = *reinterpret_cast<__half2*>(&g.y); \
    float2 u0_ = __half22float2(h0_); float2 u1_ = __half22float2(h1_); \
    a0 += wv * u0_.x; a1 += wv * u0_.y; a2 += wv * u1_.x; a3 += wv * u1_.y; }

template<int FINAL>
__global__ __launch_bounds__(256) void spmm_h_kernel(
        const __half* __restrict__ in, const __half* __restrict__ xh,
        float* __restrict__ outf, __half* __restrict__ outh,
        const int* __restrict__ row_ptr, const int2* __restrict__ cw,
        const float* __restrict__ dinv,
        int n, float scale) {
    int wave = threadIdx.x >> 6;
    int lane = threadIdx.x & 63;
    int r = blockIdx.x * 4 + wave;
    if (r >= n) return;

    int start = row_ptr[r];
    int end   = row_ptr[r + 1];
    float dr  = dinv[r];
    float ws  = dr * dr;

    float2 xraw = ((const float2*)(xh + (size_t)r * DFEAT))[lane];

    float2 sraw = ((const float2*)(in + (size_t)r * DFEAT))[lane];
    __half2 s0 = *reinterpret_cast<__half2*>(&sraw.x);
    __half2 s1 = *reinterpret_cast<__half2*>(&sraw.y);
    float2 sf0 = __half22float2(s0), sf1 = __half22float2(s1);
    float a0 = ws * sf0.x, a1 = ws * sf0.y, a2 = ws * sf1.x, a3 = ws * sf1.y;

    int e = start;
    for (; e + 4 <= end; e += 4) {
        int2 p0 = cw[e];
        int2 p1 = cw[e + 1];
        int2 p2 = cw[e + 2];
        int2 p3 = cw[e + 3];
        float2 g0 = ((const float2*)(in + (size_t)p0.x * DFEAT))[lane];
        float2 g1 = ((const float2*)(in + (size_t)p1.x * DFEAT))[lane];
        float2 g2 = ((const float2*)(in + (size_t)p2.x * DFEAT))[lane];
        float2 g3 = ((const float2*)(in + (size_t)p3.x * DFEAT))[lane];
        ACC(g0, p0.y);
        ACC(g1, p1.y);
        ACC(g2, p2.y);
        ACC(g3, p3.y);
    }
    for (; e < end; ++e) {
        int2 p = cw[e];
        float2 g = ((const float2*)(in + (size_t)p.x * DFEAT))[lane];
        ACC(g, p.y);
    }

    __half2 x0 = *reinterpret_cast<__half2*>(&xraw.x);
    __half2 x1 = *reinterpret_cast<__half2*>(&xraw.y);
    float2 xf0 = __half22float2(x0), xf1 = __half22float2(x1);
    float o0 = scale * (BETA * a0 + ALPHA * xf0.x);
    float o1 = scale * (BETA * a1 + ALPHA * xf0.y);
    float o2 = scale * (BETA * a2 + ALPHA * xf1.x);
    float o3 = scale * (BETA * a3 + ALPHA * xf1.y);

    if (FINAL) {
        ((float4*)(outf + (size_t)r * DFEAT))[lane] = make_float4(o0, o1, o2, o3);
    } else {
        __half2 h0 = __floats2half2_rn(o0, o1);
        __half2 h1 = __floats2half2_rn(o2, o3);
        float2 o;
        o.x = *reinterpret_cast<float*>(&h0);
        o.y = *reinterpret_cast<float*>(&h1);
        ((float2*)(outh + (size_t)r * DFEAT))[lane] = o;
    }
}

// ---------------- launch ----------------

extern "C" void kernel_launch(void* const* d_in, const int* in_sizes, int n_in,
                              void* d_out, int out_size, void* d_ws, size_t ws_size,
                              hipStream_t stream) {
    const float* x  = (const float*)d_in[0];
    const float* ew = (const float*)d_in[1];
    const int*   ei = (const int*)d_in[2];
    int n = in_sizes[0] / DFEAT;
    int E = in_sizes[1];
    const int* row = ei;
    const int* col = ei + E;
    float* out = (float*)d_out;

    char* ws = (char*)d_ws;
    auto alloc = [&](size_t bytes) {
        char* p = ws;
        ws += (bytes + 255) & ~(size_t)255;
        return p;
    };
    float*  deg     = (float*)alloc((size_t)n * 4);   // becomes dinv in place
    int*    counts  = (int*)  alloc((size_t)n * 4);
    int*    row_ptr = (int*)  alloc((size_t)(n + 1) * 4);
    int*    fill    = (int*)  alloc((size_t)n * 4);
    int*    partial = (int*)  alloc((size_t)1024 * 4);
    int2*   cw      = (int2*) alloc((size_t)E * 8);
    __half* xh      = (__half*)alloc((size_t)n * DFEAT * 2);
    __half* H0      = (__half*)alloc((size_t)n * DFEAT * 2);
    __half* H1      = (__half*)d_out;   // alias: dead before final fp32 write

    hipMemsetAsync(deg, 0, (size_t)n * 4, stream);
    hipMemsetAsync(counts, 0, (size_t)n * 4, stream);

    count_deg_kernel<<<(E + 255) / 256, 256, 0, stream>>>(row, ew, deg, counts, E);
    dinv_kernel<<<(n + 255) / 256, 256, 0, stream>>>(deg, n);

    int nb = (n + SCAN_CHUNK - 1) / SCAN_CHUNK;   // 49 for n=100k
    scan1_kernel<<<nb, 256, 0, stream>>>(counts, row_ptr, partial, n);
    scan2_kernel<<<1, 1024, 0, stream>>>(partial, nb);
    scan3_kernel<<<(n + 256) / 256, 256, 0, stream>>>(row_ptr, fill, partial, n, E);

    scatter_kernel<<<(E + 255) / 256, 256, 0, stream>>>(row, col, ew, deg, fill, cw, E);

    size_t n4 = (size_t)n * DFEAT / 4;
    f2h_kernel<<<(int)((n4 + 255) / 256), 256, 0, stream>>>(x, xh, n4);

    // GAMMA == 1.0 exactly for these constants, but compute anyway.
    double gamma = pow((double)BETA, KITER);
    for (int i = 0; i < KITER; ++i) gamma += (double)ALPHA * pow((double)BETA, i);
    float inv_gamma = (float)(1.0 / gamma);

    int grid = (n + 3) / 4;
    const __half* cur = xh;
    __half* bufs[2] = { H0, H1 };   // k even -> H0, k odd -> H1(d_out alias)
    for (int k = 0; k < KITER; ++k) {
        if (k < KITER - 1) {
            __half* o = bufs[k & 1];
            spmm_h_kernel<0><<<grid, 256, 0, stream>>>(cur, xh, nullptr, o,
                                                       row_ptr, cw, deg, n, 1.0f);
            cur = o;
        } else {
            spmm_h_kernel<1><<<grid, 256, 0, stream>>>(cur, xh, out, nullptr,
                                                       row_ptr, cw, deg, n, inv_gamma);
        }
    }
}

// Round 4
// 1447.285 us; speedup vs baseline: 2.0536x; 1.0745x over previous
//
#include <hip/hip_runtime.h>
#include <hip/hip_fp16.h>
#include <math.h>

#define DFEAT 256
#define KITER 10
#define ALPHA 0.1f
#define BETA 0.9f
#define SCAN_CHUNK 2048   // per 256-thread block, 8 elems/thread

#define WSCALE 268435456.0   // 2^28 fixed-point for edge weights
#define CNT_SHIFT 40

// ---------------- setup kernels ----------------

// One exact u64 atomic per edge: high bits count, low bits fixed-point weight sum.
// Returned old value yields this edge's rank within its row (old >> 40).
__global__ void edge_pass1_kernel(const int* __restrict__ row,
                                  const float* __restrict__ w,
                                  unsigned long long* __restrict__ pk,
                                  int* __restrict__ rank, int E) {
    int e = blockIdx.x * 256 + threadIdx.x;
    if (e < E) {
        int r = row[e];
        unsigned long long add = (1ULL << CNT_SHIFT) |
            (unsigned long long)((double)w[e] * WSCALE);
        unsigned long long old = atomicAdd(&pk[r], add);
        rank[e] = (int)(old >> CNT_SHIFT);
    }
}

// dinv[i] = rsqrt(deg_i + 1), deg from packed low bits.
__global__ void dinv_kernel(const unsigned long long* __restrict__ pk,
                            float* __restrict__ dinv, int n) {
    int i = blockIdx.x * 256 + threadIdx.x;
    if (i < n) {
        unsigned long long v = pk[i];
        float deg = (float)((double)(v & ((1ULL << CNT_SHIFT) - 1)) * (1.0 / WSCALE));
        dinv[i] = rsqrtf(deg + 1.0f);
    }
}

// --- hierarchical scan of counts (extracted from pk) -> row_ptr ---

__global__ __launch_bounds__(256) void scan1_kernel(const unsigned long long* __restrict__ pk,
                                                    int* __restrict__ row_ptr,
                                                    int* __restrict__ partial, int n) {
    __shared__ int wsum[4];
    int b = blockIdx.x;
    int base = b * SCAN_CHUNK;
    int tid = threadIdx.x;
    int lane = tid & 63, wv = tid >> 6;

    int v[8];
    int s = 0;
    #pragma unroll
    for (int j = 0; j < 8; ++j) {
        int i = base + tid * 8 + j;
        v[j] = (i < n) ? (int)(pk[i] >> CNT_SHIFT) : 0;
        s += v[j];
    }
    int incl = s;
    #pragma unroll
    for (int off = 1; off < 64; off <<= 1) {
        int t = __shfl_up(incl, off, 64);
        if (lane >= off) incl += t;
    }
    if (lane == 63) wsum[wv] = incl;
    __syncthreads();
    int woff = 0;
    for (int w = 0; w < wv; ++w) woff += wsum[w];
    int run = woff + incl - s;
    #pragma unroll
    for (int j = 0; j < 8; ++j) {
        int i = base + tid * 8 + j;
        if (i < n) row_ptr[i] = run;
        run += v[j];
    }
    if (tid == 255) partial[b] = run;
}

__global__ void scan2_kernel(int* __restrict__ partial, int nb) {
    __shared__ int tmp[1024];
    int tid = threadIdx.x;
    int v = (tid < nb) ? partial[tid] : 0;
    tmp[tid] = v;
    __syncthreads();
    for (int off = 1; off < 1024; off <<= 1) {
        int t = (tid >= off) ? tmp[tid - off] : 0;
        __syncthreads();
        tmp[tid] += t;
        __syncthreads();
    }
    if (tid < nb) partial[tid] = tmp[tid] - v;
}

__global__ void scan3_kernel(int* __restrict__ row_ptr,
                             const int* __restrict__ partial, int n, int E) {
    int i = blockIdx.x * 256 + threadIdx.x;
    if (i < n) {
        row_ptr[i] += partial[i / SCAN_CHUNK];
    } else if (i == n) {
        row_ptr[n] = E;
    }
}

// Atomic-free scatter: pos = row_ptr[r] + rank[e]; store RAW weight (g-space).
__global__ void scatter_kernel(const int* __restrict__ row, const int* __restrict__ col,
                               const float* __restrict__ w, const int* __restrict__ rank,
                               const int* __restrict__ row_ptr,
                               int2* __restrict__ cw, int E) {
    int e = blockIdx.x * 256 + threadIdx.x;
    if (e < E) {
        int r = row[e];
        int pos = row_ptr[r] + rank[e];
        cw[pos] = make_int2(col[e], __float_as_int(w[e]));
    }
}

// x' = dinv[row] * x, stored fp16 (g-space initial state AND the alpha term).
__global__ void xprime_kernel(const float* __restrict__ x, const float* __restrict__ dinv,
                              __half* __restrict__ dst, size_t n4) {
    size_t i = (size_t)blockIdx.x * 256 + threadIdx.x;
    if (i < n4) {
        float4 v = ((const float4*)x)[i];
        float dr = dinv[i >> 6];   // 64 float4's per row of 256 feats
        __half2 h0 = __floats2half2_rn(dr * v.x, dr * v.y);
        __half2 h1 = __floats2half2_rn(dr * v.z, dr * v.w);
        float2 o;
        o.x = *reinterpret_cast<float*>(&h0);
        o.y = *reinterpret_cast<float*>(&h1);
        ((float2*)dst)[i] = o;
    }
}

// ---------------- main SpMM iteration (g-space, fp16 state, fp32 accum) ----
// g'[r] = BETA*dr^2*( sum_e w_e*g[c_e] + g[r] ) + ALPHA*x'[r]
// final: out[r] = g'[r] / (dr * GAMMA)
#define ACC(g, wbits) { float wv = __int_as_float(wbits); \
    __half2 h0_ = *reinterpret_cast<__half2*>(&g.x); \
    __half2 h1_ = *reinterpret_cast<__half2*>(&g.y); \
    float2 u0_ = __half22float2(h0_); float2 u1_ = __half22float2(h1_); \
    a0 += wv * u0_.x; a1 += wv * u0_.y; a2 += wv * u1_.x; a3 += wv * u1_.y; }

template<int FINAL>
__global__ __launch_bounds__(256) void spmm_h_kernel(
        const __half* __restrict__ in, const __half* __restrict__ xh,
        float* __restrict__ outf, __half* __restrict__ outh,
        const int* __restrict__ row_ptr, const int2* __restrict__ cw,
        const float* __restrict__ dinv,
        int n, float inv_gamma) {
    int wave = threadIdx.x >> 6;
    int lane = threadIdx.x & 63;
    int r = blockIdx.x * 4 + wave;
    if (r >= n) return;

    int start = row_ptr[r];
    int end   = row_ptr[r + 1];
    float dr  = dinv[r];
    float c1  = BETA * dr * dr;

    float2 xraw = ((const float2*)(xh + (size_t)r * DFEAT))[lane];

    // self term, weight exactly 1
    float2 sraw = ((const float2*)(in + (size_t)r * DFEAT))[lane];
    __half2 s0 = *reinterpret_cast<__half2*>(&sraw.x);
    __half2 s1 = *reinterpret_cast<__half2*>(&sraw.y);
    float2 sf0 = __half22float2(s0), sf1 = __half22float2(s1);
    float a0 = sf0.x, a1 = sf0.y, a2 = sf1.x, a3 = sf1.y;

    int e = start;
    for (; e + 4 <= end; e += 4) {
        int2 p0 = cw[e];
        int2 p1 = cw[e + 1];
        int2 p2 = cw[e + 2];
        int2 p3 = cw[e + 3];
        float2 g0 = ((const float2*)(in + (size_t)p0.x * DFEAT))[lane];
        float2 g1 = ((const float2*)(in + (size_t)p1.x * DFEAT))[lane];
        float2 g2 = ((const float2*)(in + (size_t)p2.x * DFEAT))[lane];
        float2 g3 = ((const float2*)(in + (size_t)p3.x * DFEAT))[lane];
        ACC(g0, p0.y);
        ACC(g1, p1.y);
        ACC(g2, p2.y);
        ACC(g3, p3.y);
    }
    for (; e < end; ++e) {
        int2 p = cw[e];
        float2 g = ((const float2*)(in + (size_t)p.x * DFEAT))[lane];
        ACC(g, p.y);
    }

    __half2 x0 = *reinterpret_cast<__half2*>(&xraw.x);
    __half2 x1 = *reinterpret_cast<__half2*>(&xraw.y);
    float2 xf0 = __half22float2(x0), xf1 = __half22float2(x1);
    float o0 = c1 * a0 + ALPHA * xf0.x;
    float o1 = c1 * a1 + ALPHA * xf0.y;
    float o2 = c1 * a2 + ALPHA * xf1.x;
    float o3 = c1 * a3 + ALPHA * xf1.y;

    if (FINAL) {
        float up = inv_gamma / dr;   // back to h-space
        ((float4*)(outf + (size_t)r * DFEAT))[lane] =
            make_float4(o0 * up, o1 * up, o2 * up, o3 * up);
    } else {
        __half2 h0 = __floats2half2_rn(o0, o1);
        __half2 h1 = __floats2half2_rn(o2, o3);
        float2 o;
        o.x = *reinterpret_cast<float*>(&h0);
        o.y = *reinterpret_cast<float*>(&h1);
        ((float2*)(outh + (size_t)r * DFEAT))[lane] = o;
    }
}

// ---------------- launch ----------------

extern "C" void kernel_launch(void* const* d_in, const int* in_sizes, int n_in,
                              void* d_out, int out_size, void* d_ws, size_t ws_size,
                              hipStream_t stream) {
    const float* x  = (const float*)d_in[0];
    const float* ew = (const float*)d_in[1];
    const int*   ei = (const int*)d_in[2];
    int n = in_sizes[0] / DFEAT;
    int E = in_sizes[1];
    const int* row = ei;
    const int* col = ei + E;
    float* out = (float*)d_out;

    char* ws = (char*)d_ws;
    auto alloc = [&](size_t bytes) {
        char* p = ws;
        ws += (bytes + 255) & ~(size_t)255;
        return p;
    };
    unsigned long long* pk = (unsigned long long*)alloc((size_t)n * 8);
    int*    rank    = (int*)  alloc((size_t)E * 4);
    int*    row_ptr = (int*)  alloc((size_t)(n + 1) * 4);
    int*    partial = (int*)  alloc((size_t)1024 * 4);
    float*  dinv    = (float*)alloc((size_t)n * 4);
    int2*   cw      = (int2*) alloc((size_t)E * 8);
    __half* xh      = (__half*)alloc((size_t)n * DFEAT * 2);
    __half* H0      = (__half*)alloc((size_t)n * DFEAT * 2);
    __half* H1      = (__half*)d_out;   // alias: dead before final fp32 write

    hipMemsetAsync(pk, 0, (size_t)n * 8, stream);

    edge_pass1_kernel<<<(E + 255) / 256, 256, 0, stream>>>(row, ew, pk, rank, E);
    dinv_kernel<<<(n + 255) / 256, 256, 0, stream>>>(pk, dinv, n);

    int nb = (n + SCAN_CHUNK - 1) / SCAN_CHUNK;
    scan1_kernel<<<nb, 256, 0, stream>>>(pk, row_ptr, partial, n);
    scan2_kernel<<<1, 1024, 0, stream>>>(partial, nb);
    scan3_kernel<<<(n + 256) / 256, 256, 0, stream>>>(row_ptr, partial, n, E);

    scatter_kernel<<<(E + 255) / 256, 256, 0, stream>>>(row, col, ew, rank, row_ptr, cw, E);

    size_t n4 = (size_t)n * DFEAT / 4;
    xprime_kernel<<<(int)((n4 + 255) / 256), 256, 0, stream>>>(x, dinv, xh, n4);

    // GAMMA == 1.0 exactly for these constants, but compute anyway.
    double gamma = pow((double)BETA, KITER);
    for (int i = 0; i < KITER; ++i) gamma += (double)ALPHA * pow((double)BETA, i);
    float inv_gamma = (float)(1.0 / gamma);

    int grid = (n + 3) / 4;
    const __half* cur = xh;
    __half* bufs[2] = { H0, H1 };   // k even -> H0, k odd -> H1(d_out alias)
    for (int k = 0; k < KITER; ++k) {
        if (k < KITER - 1) {
            __half* o = bufs[k & 1];
            spmm_h_kernel<0><<<grid, 256, 0, stream>>>(cur, xh, nullptr, o,
                                                       row_ptr, cw, dinv, n, 1.0f);
            cur = o;
        } else {
            spmm_h_kernel<1><<<grid, 256, 0, stream>>>(cur, xh, out, nullptr,
                                                       row_ptr, cw, dinv, n, inv_gamma);
        }
    }
}

// Round 5
// 1431.977 us; speedup vs baseline: 2.0756x; 1.0107x over previous
//
#include <hip/hip_runtime.h>
#include <hip/hip_fp16.h>
#include <math.h>

#define DFEAT 256
#define KITER 10
#define ALPHA 0.1f
#define BETA 0.9f
#define SCAN_CHUNK 2048   // per 256-thread block, 8 elems/thread

#define WSCALE 268435456.0   // 2^28 fixed-point for edge weights
#define CNT_SHIFT 40

// ---------------- setup kernels ----------------

// One exact u64 atomic per edge: high bits count, low bits fixed-point weight sum.
// Returned old value yields this edge's rank within its row (old >> 40).
__global__ void edge_pass1_kernel(const int* __restrict__ row,
                                  const float* __restrict__ w,
                                  unsigned long long* __restrict__ pk,
                                  int* __restrict__ rank, int E) {
    int e = blockIdx.x * 256 + threadIdx.x;
    if (e < E) {
        int r = row[e];
        unsigned long long add = (1ULL << CNT_SHIFT) |
            (unsigned long long)((double)w[e] * WSCALE);
        unsigned long long old = atomicAdd(&pk[r], add);
        rank[e] = (int)(old >> CNT_SHIFT);
    }
}

// dinv[i] = rsqrt(deg_i + 1), deg from packed low bits.
__global__ void dinv_kernel(const unsigned long long* __restrict__ pk,
                            float* __restrict__ dinv, int n) {
    int i = blockIdx.x * 256 + threadIdx.x;
    if (i < n) {
        unsigned long long v = pk[i];
        float deg = (float)((double)(v & ((1ULL << CNT_SHIFT) - 1)) * (1.0 / WSCALE));
        dinv[i] = rsqrtf(deg + 1.0f);
    }
}

// --- hierarchical scan of counts (extracted from pk) -> row_ptr ---

__global__ __launch_bounds__(256) void scan1_kernel(const unsigned long long* __restrict__ pk,
                                                    int* __restrict__ row_ptr,
                                                    int* __restrict__ partial, int n) {
    __shared__ int wsum[4];
    int b = blockIdx.x;
    int base = b * SCAN_CHUNK;
    int tid = threadIdx.x;
    int lane = tid & 63, wv = tid >> 6;

    int v[8];
    int s = 0;
    #pragma unroll
    for (int j = 0; j < 8; ++j) {
        int i = base + tid * 8 + j;
        v[j] = (i < n) ? (int)(pk[i] >> CNT_SHIFT) : 0;
        s += v[j];
    }
    int incl = s;
    #pragma unroll
    for (int off = 1; off < 64; off <<= 1) {
        int t = __shfl_up(incl, off, 64);
        if (lane >= off) incl += t;
    }
    if (lane == 63) wsum[wv] = incl;
    __syncthreads();
    int woff = 0;
    for (int w = 0; w < wv; ++w) woff += wsum[w];
    int run = woff + incl - s;
    #pragma unroll
    for (int j = 0; j < 8; ++j) {
        int i = base + tid * 8 + j;
        if (i < n) row_ptr[i] = run;
        run += v[j];
    }
    if (tid == 255) partial[b] = run;
}

__global__ void scan2_kernel(int* __restrict__ partial, int nb) {
    __shared__ int tmp[1024];
    int tid = threadIdx.x;
    int v = (tid < nb) ? partial[tid] : 0;
    tmp[tid] = v;
    __syncthreads();
    for (int off = 1; off < 1024; off <<= 1) {
        int t = (tid >= off) ? tmp[tid - off] : 0;
        __syncthreads();
        tmp[tid] += t;
        __syncthreads();
    }
    if (tid < nb) partial[tid] = tmp[tid] - v;
}

__global__ void scan3_kernel(int* __restrict__ row_ptr,
                             const int* __restrict__ partial, int n, int E) {
    int i = blockIdx.x * 256 + threadIdx.x;
    if (i < n) {
        row_ptr[i] += partial[i / SCAN_CHUNK];
    } else if (i == n) {
        row_ptr[n] = E;
    }
}

// Atomic-free scatter: pos = row_ptr[r] + rank[e]; store RAW weight (g-space).
__global__ void scatter_kernel(const int* __restrict__ row, const int* __restrict__ col,
                               const float* __restrict__ w, const int* __restrict__ rank,
                               const int* __restrict__ row_ptr,
                               int2* __restrict__ cw, int E) {
    int e = blockIdx.x * 256 + threadIdx.x;
    if (e < E) {
        int r = row[e];
        int pos = row_ptr[r] + rank[e];
        cw[pos] = make_int2(col[e], __float_as_int(w[e]));
    }
}

// x' = dinv[row] * x, stored fp16 (g-space initial state AND the alpha term).
__global__ void xprime_kernel(const float* __restrict__ x, const float* __restrict__ dinv,
                              __half* __restrict__ dst, size_t n4) {
    size_t i = (size_t)blockIdx.x * 256 + threadIdx.x;
    if (i < n4) {
        float4 v = ((const float4*)x)[i];
        float dr = dinv[i >> 6];   // 64 float4's per row of 256 feats
        __half2 h0 = __floats2half2_rn(dr * v.x, dr * v.y);
        __half2 h1 = __floats2half2_rn(dr * v.z, dr * v.w);
        float2 o;
        o.x = *reinterpret_cast<float*>(&h0);
        o.y = *reinterpret_cast<float*>(&h1);
        ((float2*)dst)[i] = o;
    }
}

// ---------------- main SpMM iteration (g-space, fp16 state, fp32 accum) ----
// g'[r] = BETA*dr^2*( sum_e w_e*g[c_e] + g[r] ) + ALPHA*x'[r]
// final: out[r] = g'[r] / (dr * GAMMA)
// One wave per row; lane owns 4 feats (8B fp16 per lane).
// Edge loop unrolled 8-deep: 8 independent cw loads, then 8 independent
// 512B row-gathers in flight per wave (latency-bound fix, R5).
#define ACC(g, wbits) { float wv = __int_as_float(wbits); \
    __half2 h0_ = *reinterpret_cast<__half2*>(&g.x); \
    __half2 h1_ = *reinterpret_cast<__half2*>(&g.y); \
    float2 u0_ = __half22float2(h0_); float2 u1_ = __half22float2(h1_); \
    a0 += wv * u0_.x; a1 += wv * u0_.y; a2 += wv * u1_.x; a3 += wv * u1_.y; }

template<int FINAL>
__global__ __launch_bounds__(256) void spmm_h_kernel(
        const __half* __restrict__ in, const __half* __restrict__ xh,
        float* __restrict__ outf, __half* __restrict__ outh,
        const int* __restrict__ row_ptr, const int2* __restrict__ cw,
        const float* __restrict__ dinv,
        int n, float inv_gamma) {
    int wave = threadIdx.x >> 6;
    int lane = threadIdx.x & 63;
    int r = blockIdx.x * 4 + wave;
    if (r >= n) return;

    int start = row_ptr[r];
    int end   = row_ptr[r + 1];
    float dr  = dinv[r];
    float c1  = BETA * dr * dr;

    const float2* inf2 = (const float2*)in;
    unsigned rbase = ((unsigned)r << 6) | (unsigned)lane;   // 64 float2 per row

    float2 xraw = ((const float2*)xh)[rbase];

    // self term, weight exactly 1
    float2 sraw = inf2[rbase];
    __half2 s0 = *reinterpret_cast<__half2*>(&sraw.x);
    __half2 s1 = *reinterpret_cast<__half2*>(&sraw.y);
    float2 sf0 = __half22float2(s0), sf1 = __half22float2(s1);
    float a0 = sf0.x, a1 = sf0.y, a2 = sf1.x, a3 = sf1.y;

    int e = start;
    for (; e + 8 <= end; e += 8) {
        int2 p0 = cw[e];
        int2 p1 = cw[e + 1];
        int2 p2 = cw[e + 2];
        int2 p3 = cw[e + 3];
        int2 p4 = cw[e + 4];
        int2 p5 = cw[e + 5];
        int2 p6 = cw[e + 6];
        int2 p7 = cw[e + 7];
        float2 g0 = inf2[((unsigned)p0.x << 6) | (unsigned)lane];
        float2 g1 = inf2[((unsigned)p1.x << 6) | (unsigned)lane];
        float2 g2 = inf2[((unsigned)p2.x << 6) | (unsigned)lane];
        float2 g3 = inf2[((unsigned)p3.x << 6) | (unsigned)lane];
        float2 g4 = inf2[((unsigned)p4.x << 6) | (unsigned)lane];
        float2 g5 = inf2[((unsigned)p5.x << 6) | (unsigned)lane];
        float2 g6 = inf2[((unsigned)p6.x << 6) | (unsigned)lane];
        float2 g7 = inf2[((unsigned)p7.x << 6) | (unsigned)lane];
        ACC(g0, p0.y);
        ACC(g1, p1.y);
        ACC(g2, p2.y);
        ACC(g3, p3.y);
        ACC(g4, p4.y);
        ACC(g5, p5.y);
        ACC(g6, p6.y);
        ACC(g7, p7.y);
    }
    for (; e + 4 <= end; e += 4) {
        int2 p0 = cw[e];
        int2 p1 = cw[e + 1];
        int2 p2 = cw[e + 2];
        int2 p3 = cw[e + 3];
        float2 g0 = inf2[((unsigned)p0.x << 6) | (unsigned)lane];
        float2 g1 = inf2[((unsigned)p1.x << 6) | (unsigned)lane];
        float2 g2 = inf2[((unsigned)p2.x << 6) | (unsigned)lane];
        float2 g3 = inf2[((unsigned)p3.x << 6) | (unsigned)lane];
        ACC(g0, p0.y);
        ACC(g1, p1.y);
        ACC(g2, p2.y);
        ACC(g3, p3.y);
    }
    for (; e < end; ++e) {
        int2 p = cw[e];
        float2 g = inf2[((unsigned)p.x << 6) | (unsigned)lane];
        ACC(g, p.y);
    }

    __half2 x0 = *reinterpret_cast<__half2*>(&xraw.x);
    __half2 x1 = *reinterpret_cast<__half2*>(&xraw.y);
    float2 xf0 = __half22float2(x0), xf1 = __half22float2(x1);
    float o0 = c1 * a0 + ALPHA * xf0.x;
    float o1 = c1 * a1 + ALPHA * xf0.y;
    float o2 = c1 * a2 + ALPHA * xf1.x;
    float o3 = c1 * a3 + ALPHA * xf1.y;

    if (FINAL) {
        float up = inv_gamma / dr;   // back to h-space
        ((float4*)(outf + (size_t)r * DFEAT))[lane] =
            make_float4(o0 * up, o1 * up, o2 * up, o3 * up);
    } else {
        __half2 h0 = __floats2half2_rn(o0, o1);
        __half2 h1 = __floats2half2_rn(o2, o3);
        float2 o;
        o.x = *reinterpret_cast<float*>(&h0);
        o.y = *reinterpret_cast<float*>(&h1);
        ((float2*)outh)[rbase] = o;
    }
}

// ---------------- launch ----------------

extern "C" void kernel_launch(void* const* d_in, const int* in_sizes, int n_in,
                              void* d_out, int out_size, void* d_ws, size_t ws_size,
                              hipStream_t stream) {
    const float* x  = (const float*)d_in[0];
    const float* ew = (const float*)d_in[1];
    const int*   ei = (const int*)d_in[2];
    int n = in_sizes[0] / DFEAT;
    int E = in_sizes[1];
    const int* row = ei;
    const int* col = ei + E;
    float* out = (float*)d_out;

    char* ws = (char*)d_ws;
    auto alloc = [&](size_t bytes) {
        char* p = ws;
        ws += (bytes + 255) & ~(size_t)255;
        return p;
    };
    unsigned long long* pk = (unsigned long long*)alloc((size_t)n * 8);
    int*    rank    = (int*)  alloc((size_t)E * 4);
    int*    row_ptr = (int*)  alloc((size_t)(n + 1) * 4);
    int*    partial = (int*)  alloc((size_t)1024 * 4);
    float*  dinv    = (float*)alloc((size_t)n * 4);
    int2*   cw      = (int2*) alloc((size_t)E * 8);
    __half* xh      = (__half*)alloc((size_t)n * DFEAT * 2);
    __half* H0      = (__half*)alloc((size_t)n * DFEAT * 2);
    __half* H1      = (__half*)d_out;   // alias: dead before final fp32 write

    hipMemsetAsync(pk, 0, (size_t)n * 8, stream);

    edge_pass1_kernel<<<(E + 255) / 256, 256, 0, stream>>>(row, ew, pk, rank, E);
    dinv_kernel<<<(n + 255) / 256, 256, 0, stream>>>(pk, dinv, n);

    int nb = (n + SCAN_CHUNK - 1) / SCAN_CHUNK;
    scan1_kernel<<<nb, 256, 0, stream>>>(pk, row_ptr, partial, n);
    scan2_kernel<<<1, 1024, 0, stream>>>(partial, nb);
    scan3_kernel<<<(n + 256) / 256, 256, 0, stream>>>(row_ptr, partial, n, E);

    scatter_kernel<<<(E + 255) / 256, 256, 0, stream>>>(row, col, ew, rank, row_ptr, cw, E);

    size_t n4 = (size_t)n * DFEAT / 4;
    xprime_kernel<<<(int)((n4 + 255) / 256), 256, 0, stream>>>(x, dinv, xh, n4);

    // GAMMA == 1.0 exactly for these constants, but compute anyway.
    double gamma = pow((double)BETA, KITER);
    for (int i = 0; i < KITER; ++i) gamma += (double)ALPHA * pow((double)BETA, i);
    float inv_gamma = (float)(1.0 / gamma);

    int grid = (n + 3) / 4;
    const __half* cur = xh;
    __half* bufs[2] = { H0, H1 };   // k even -> H0, k odd -> H1(d_out alias)
    for (int k = 0; k < KITER; ++k) {
        if (k < KITER - 1) {
            __half* o = bufs[k & 1];
            spmm_h_kernel<0><<<grid, 256, 0, stream>>>(cur, xh, nullptr, o,
                                                       row_ptr, cw, dinv, n, 1.0f);
            cur = o;
        } else {
            spmm_h_kernel<1><<<grid, 256, 0, stream>>>(cur, xh, out, nullptr,
                                                       row_ptr, cw, dinv, n, inv_gamma);
        }
    }
}